// Round 1
// baseline (520.264 us; speedup 1.0000x reference)
//
#include <hip/hip_runtime.h>

// Problem constants (from reference)
#define N_PTS 8388608
#define FX 758.03967f
#define CXC 621.46572f
#define FY 761.62359f
#define CYC 756.86402f
#define U_MAX 1231.0f   // WIDTH - 1
#define W_MAX 1615.0f   // HEIGHT - 1
#define MIN_D 1.0f
#define MAX_D_R 10.0f
#define MAX_D_M 5.0f

// Workspace layout (floats): [0..8] R row-major, [9..11] t, [12] uint counter

__global__ void pose_setup_kernel(const float* __restrict__ x, const float* __restrict__ y,
                                  const float* __restrict__ z, const float* __restrict__ roll,
                                  const float* __restrict__ pitch, const float* __restrict__ yaw,
                                  float* __restrict__ ws) {
    float cr = cosf(*roll), sr = sinf(*roll);
    float cp = cosf(*pitch), sp = sinf(*pitch);
    float cy = cosf(*yaw),  sy = sinf(*yaw);
    // R = Rx(roll) @ Ry(pitch) @ Rz(yaw), row-major. At the zero pose this is
    // exactly identity (with signed zeros), so v = points bit-exact.
    ws[0] = cp * cy;                ws[1] = -(cp * sy);             ws[2] = sp;
    ws[3] = cr * sy + sr * sp * cy; ws[4] = cr * cy - sr * sp * sy; ws[5] = -(sr * cp);
    ws[6] = sr * sy - cr * sp * cy; ws[7] = sr * cy + cr * sp * sy; ws[8] = cr * cp;
    ws[9] = *x; ws[10] = *y; ws[11] = *z;
    ((unsigned int*)ws)[12] = 0u;   // reward counter (ws is poisoned 0xAA each call)
}

__global__ __launch_bounds__(256) void frustum_kernel(const float4* __restrict__ pts,
                                                      const float* __restrict__ ws,
                                                      float4* __restrict__ out) {
    const float R0 = ws[0], R1 = ws[1], R2 = ws[2];
    const float R3 = ws[3], R4 = ws[4], R5 = ws[5];
    const float R6 = ws[6], R7 = ws[7], R8 = ws[8];
    const float t0 = ws[9], t1 = ws[10], t2 = ws[11];

    const int tid = blockIdx.x * 256 + threadIdx.x;   // one thread = 4 points = 3 float4
    const long base = (long)tid * 3;
    float4 q0 = pts[base + 0];
    float4 q1 = pts[base + 1];
    float4 q2 = pts[base + 2];

    int cnt = 0;
    auto proc = [&](float px, float py, float pz, float& ox, float& oy, float& oz) {
        float d0 = px - t0, d1 = py - t1, d2 = pz - t2;
        // ascending-k fma accumulation to match the numpy reference's matmul
        float v0 = fmaf(d2, R6, fmaf(d1, R3, d0 * R0));
        float v1 = fmaf(d2, R7, fmaf(d1, R4, d0 * R1));
        float v2 = fmaf(d2, R8, fmaf(d1, R5, d0 * R2));
        float p0 = fmaf(v2, CXC, v0 * FX);
        float p1 = fmaf(v2, CYC, v1 * FY);
        float u = p0 / v2;           // IEEE div; inf/nan on v2==0 compares false, same as numpy mask
        float w = p1 / v2;
        bool fov = (v2 > 0.0f) && (u > 1.0f) && (u < U_MAX) && (w > 1.0f) && (w < W_MAX);
        if (fov && (v2 > MIN_D) && (v2 < MAX_D_R)) cnt++;
        bool m = fov && (v2 > MIN_D) && (v2 < MAX_D_M);
        ox = m ? v0 : 0.0f;
        oy = m ? v1 : 0.0f;
        oz = m ? v2 : 0.0f;
    };

    float4 o0, o1, o2;
    proc(q0.x, q0.y, q0.z, o0.x, o0.y, o0.z);   // point 0
    proc(q0.w, q1.x, q1.y, o0.w, o1.x, o1.y);   // point 1
    proc(q1.z, q1.w, q2.x, o1.z, o1.w, o2.x);   // point 2
    proc(q2.y, q2.z, q2.w, o2.y, o2.z, o2.w);   // point 3

    out[base + 0] = o0;
    out[base + 1] = o1;
    out[base + 2] = o2;

    // wave-level reduction (wave = 64 on CDNA), one atomic per wave
    for (int off = 32; off > 0; off >>= 1) cnt += __shfl_down(cnt, off, 64);
    if ((threadIdx.x & 63) == 0 && cnt > 0) {
        atomicAdd((unsigned int*)ws + 12, (unsigned int)cnt);
    }
}

__global__ void finalize_kernel(const float* __restrict__ ws, float* __restrict__ out) {
    unsigned int c = ((const unsigned int*)ws)[12];
    out[(long)3 * N_PTS] = 1.0f / ((float)c + 1e-6f);
}

extern "C" void kernel_launch(void* const* d_in, const int* in_sizes, int n_in,
                              void* d_out, int out_size, void* d_ws, size_t ws_size,
                              hipStream_t stream) {
    const float* points = (const float*)d_in[0];
    const float* x      = (const float*)d_in[1];
    const float* y      = (const float*)d_in[2];
    const float* z      = (const float*)d_in[3];
    const float* roll   = (const float*)d_in[4];
    const float* pitch  = (const float*)d_in[5];
    const float* yaw    = (const float*)d_in[6];
    float* ws = (float*)d_ws;
    float* out = (float*)d_out;

    pose_setup_kernel<<<1, 1, 0, stream>>>(x, y, z, roll, pitch, yaw, ws);

    const int threads = 256;
    const int n_thread_units = N_PTS / 4;            // 4 points per thread
    const int blocks = n_thread_units / threads;     // 8192
    frustum_kernel<<<blocks, threads, 0, stream>>>((const float4*)points, ws, (float4*)out);

    finalize_kernel<<<1, 1, 0, stream>>>(ws, out);
}

// Round 2
// 197.387 us; speedup vs baseline: 2.6358x; 2.6358x over previous
//
#include <hip/hip_runtime.h>

// Problem constants (from reference)
#define N_PTS 8388608
#define FX 758.03967f
#define CXC 621.46572f
#define FY 761.62359f
#define CYC 756.86402f
#define U_MAX 1231.0f   // WIDTH - 1
#define W_MAX 1615.0f   // HEIGHT - 1
#define MIN_D 1.0f
#define MAX_D_R 10.0f
#define MAX_D_M 5.0f

#define N_SLOTS 64
#define SLOT_STRIDE 32   // floats -> 128 B, one cacheline per slot (kills cross-slot contention)

// Workspace layout (floats):
//   [0..8]   R row-major
//   [9..11]  t
//   [16 + i*SLOT_STRIDE]  (i in [0,64))  : uint partial counters

__global__ void pose_setup_kernel(const float* __restrict__ x, const float* __restrict__ y,
                                  const float* __restrict__ z, const float* __restrict__ roll,
                                  const float* __restrict__ pitch, const float* __restrict__ yaw,
                                  float* __restrict__ ws) {
    int tid = threadIdx.x;
    if (tid == 0) {
        float cr = cosf(*roll), sr = sinf(*roll);
        float cp = cosf(*pitch), sp = sinf(*pitch);
        float cy = cosf(*yaw),  sy = sinf(*yaw);
        // R = Rx(roll) @ Ry(pitch) @ Rz(yaw), row-major. At the zero pose this is
        // exactly identity (with signed zeros), so v = points bit-exact.
        ws[0] = cp * cy;                ws[1] = -(cp * sy);             ws[2] = sp;
        ws[3] = cr * sy + sr * sp * cy; ws[4] = cr * cy - sr * sp * sy; ws[5] = -(sr * cp);
        ws[6] = sr * sy - cr * sp * cy; ws[7] = sr * cy + cr * sp * sy; ws[8] = cr * cp;
        ws[9] = *x; ws[10] = *y; ws[11] = *z;
    }
    if (tid < N_SLOTS) {
        ((unsigned int*)ws)[16 + tid * SLOT_STRIDE] = 0u;   // ws is re-poisoned 0xAA each call
    }
}

__global__ __launch_bounds__(256) void frustum_kernel(const float4* __restrict__ pts,
                                                      const float* __restrict__ ws,
                                                      float4* __restrict__ out) {
    const float R0 = ws[0], R1 = ws[1], R2 = ws[2];
    const float R3 = ws[3], R4 = ws[4], R5 = ws[5];
    const float R6 = ws[6], R7 = ws[7], R8 = ws[8];
    const float t0 = ws[9], t1 = ws[10], t2 = ws[11];

    const int tid = blockIdx.x * 256 + threadIdx.x;   // one thread = 4 points = 3 float4
    const long base = (long)tid * 3;
    float4 q0 = pts[base + 0];
    float4 q1 = pts[base + 1];
    float4 q2 = pts[base + 2];

    int cnt = 0;
    auto proc = [&](float px, float py, float pz, float& ox, float& oy, float& oz) {
        float d0 = px - t0, d1 = py - t1, d2 = pz - t2;
        // ascending-k fma accumulation to match the numpy reference's matmul
        float v0 = fmaf(d2, R6, fmaf(d1, R3, d0 * R0));
        float v1 = fmaf(d2, R7, fmaf(d1, R4, d0 * R1));
        float v2 = fmaf(d2, R8, fmaf(d1, R5, d0 * R2));
        float p0 = fmaf(v2, CXC, v0 * FX);
        float p1 = fmaf(v2, CYC, v1 * FY);
        float u = p0 / v2;           // IEEE div; inf/nan on v2==0 compares false, same as numpy mask
        float w = p1 / v2;
        bool fov = (v2 > 0.0f) && (u > 1.0f) && (u < U_MAX) && (w > 1.0f) && (w < W_MAX);
        if (fov && (v2 > MIN_D) && (v2 < MAX_D_R)) cnt++;
        bool m = fov && (v2 > MIN_D) && (v2 < MAX_D_M);
        ox = m ? v0 : 0.0f;
        oy = m ? v1 : 0.0f;
        oz = m ? v2 : 0.0f;
    };

    float4 o0, o1, o2;
    proc(q0.x, q0.y, q0.z, o0.x, o0.y, o0.z);   // point 0
    proc(q0.w, q1.x, q1.y, o0.w, o1.x, o1.y);   // point 1
    proc(q1.z, q1.w, q2.x, o1.z, o1.w, o2.x);   // point 2
    proc(q2.y, q2.z, q2.w, o2.y, o2.z, o2.w);   // point 3

    out[base + 0] = o0;
    out[base + 1] = o1;
    out[base + 2] = o2;

    // wave reduce (wave = 64), then block reduce in LDS, then ONE atomic per
    // block into one of 64 cacheline-spaced slots. R1's single-address atomic
    // (32K waves -> 1 address) serialized at L2 and cost ~370 us.
    for (int off = 32; off > 0; off >>= 1) cnt += __shfl_down(cnt, off, 64);
    __shared__ int red[4];
    const int wave = threadIdx.x >> 6;
    if ((threadIdx.x & 63) == 0) red[wave] = cnt;
    __syncthreads();
    if (threadIdx.x == 0) {
        int s = red[0] + red[1] + red[2] + red[3];
        if (s > 0) {
            unsigned int* slot = (unsigned int*)ws + 16 + (blockIdx.x & (N_SLOTS - 1)) * SLOT_STRIDE;
            atomicAdd(slot, (unsigned int)s);
        }
    }
}

__global__ void finalize_kernel(const float* __restrict__ ws, float* __restrict__ out) {
    unsigned int c = 0;
    for (int i = 0; i < N_SLOTS; ++i)
        c += ((const unsigned int*)ws)[16 + i * SLOT_STRIDE];
    out[(long)3 * N_PTS] = 1.0f / ((float)c + 1e-6f);
}

extern "C" void kernel_launch(void* const* d_in, const int* in_sizes, int n_in,
                              void* d_out, int out_size, void* d_ws, size_t ws_size,
                              hipStream_t stream) {
    const float* points = (const float*)d_in[0];
    const float* x      = (const float*)d_in[1];
    const float* y      = (const float*)d_in[2];
    const float* z      = (const float*)d_in[3];
    const float* roll   = (const float*)d_in[4];
    const float* pitch  = (const float*)d_in[5];
    const float* yaw    = (const float*)d_in[6];
    float* ws = (float*)d_ws;
    float* out = (float*)d_out;

    pose_setup_kernel<<<1, 64, 0, stream>>>(x, y, z, roll, pitch, yaw, ws);

    const int threads = 256;
    const int n_thread_units = N_PTS / 4;            // 4 points per thread
    const int blocks = n_thread_units / threads;     // 8192
    frustum_kernel<<<blocks, threads, 0, stream>>>((const float4*)points, ws, (float4*)out);

    finalize_kernel<<<1, 1, 0, stream>>>(ws, out);
}